// Round 3
// baseline (399.330 us; speedup 1.0000x reference)
//
#include <hip/hip_runtime.h>
#include <hip/hip_bf16.h>

typedef __hip_bfloat16 bf16;
typedef __attribute__((ext_vector_type(8))) short short8;
typedef __attribute__((ext_vector_type(4))) float floatx4;

#define NVP 10242
#define NV  40962
#define NF  81920
#define VPB 32

__device__ __forceinline__ float bfbits2f(unsigned short u) {
    union { unsigned int i; float f; } cv; cv.i = ((unsigned int)u) << 16;
    return cv.f;
}
__device__ __forceinline__ unsigned short f2bfbits(float f) {
    bf16 h = __float2bfloat16(f);
    return __builtin_bit_cast(unsigned short, h);
}
// fp8 e4m3 (OCP on gfx950)
__device__ __forceinline__ unsigned char one_fp8(float a) {
    int p = __builtin_amdgcn_cvt_pk_fp8_f32(a, 0.f, 0, false);
    return (unsigned char)(p & 0xff);
}
__device__ __forceinline__ float fp8_lo(unsigned int u) {
    return __builtin_amdgcn_cvt_f32_fp8(u, 0);
}

// ---------------------------------------------------------------------------
// K0: coeffs [o][c][k] -> coeffsB bf16 in MFMA 16x16x32 B-fragment layout
// ---------------------------------------------------------------------------
__global__ void k_coeffsB(const float* __restrict__ coeffs,
                          unsigned short* __restrict__ coeffsB) {
    int t = blockIdx.x * 256 + threadIdx.x;       // 0..16383
    int j = t & 7, lane = (t >> 3) & 63, s = t >> 9;   // s = ot*8+kk
    int ot = s >> 3, kk = s & 7;
    int o  = ot * 16 + (lane & 15);
    int kg = kk * 32 + (lane >> 4) * 8 + j;
    coeffsB[t] = f2bfbits(coeffs[o * 256 + kg]);
}

// ---------------------------------------------------------------------------
// K0b: precompose F2V ∘ (EW/NS-proj) ∘ G  +  L into ONE per-vertex operator.
// Record: 96 dwords (384 B), batch-invariant, built once:
//   dw[0..3]  : 7 lap cols u16 (+1 pad col=0)
//   dw[4..7]  : 7 lap vals bf16 packed 2/dw (+pad val=0)
//   7 chunks ch=0..6 at dw[8+12ch]:
//     dw[+0..3]: 8 grad cols u16       dw[+4..11]: 8 val-pairs (ew bf16 lo | ns bf16 hi)
//   54 real grad entries (6 faces x 9), slots 54..55 pad (col0,val0).
// Removes k_facegrad + the fp8 gfi intermediate entirely.
// ---------------------------------------------------------------------------
__global__ void __launch_bounds__(256, 4) k_packOp(
    const int* __restrict__ L_cols,   const float* __restrict__ L_vals,
    const int* __restrict__ F2V_cols, const float* __restrict__ F2V_vals,
    const int* __restrict__ G_cols,   const float* __restrict__ G_vals,
    const float* __restrict__ EW,     const float* __restrict__ NS,
    unsigned int* __restrict__ Op) {
    int v = blockIdx.x * 256 + threadIdx.x;
    if (v >= NV) return;
    unsigned int r[96];
#pragma unroll
    for (int q = 0; q < 96; ++q) r[q] = 0u;
#pragma unroll
    for (int j = 0; j < 7; ++j) {
        unsigned int col = (unsigned int)L_cols[v * 7 + j];
        unsigned int val = (unsigned int)f2bfbits(L_vals[v * 7 + j]);
        r[j >> 1]       |= col << ((j & 1) * 16);
        r[4 + (j >> 1)] |= val << ((j & 1) * 16);
    }
#pragma unroll
    for (int j = 0; j < 6; ++j) {
        int   f = F2V_cols[v * 6 + j];
        float w = F2V_vals[v * 6 + j];
#pragma unroll
        for (int d = 0; d < 3; ++d) {
            float ewd = w * EW[f * 3 + d];
            float nsd = w * NS[f * 3 + d];
#pragma unroll
            for (int i = 0; i < 3; ++i) {
                int idx = (d * NF + f) * 3 + i;
                unsigned int col = (unsigned int)G_cols[idx];
                float gv = G_vals[idx];
                int e = j * 9 + d * 3 + i;          // 0..53
                int ch = e >> 3, sl = e & 7;
                int base = 8 + ch * 12;
                r[base + (sl >> 1)] |= col << ((sl & 1) * 16);
                r[base + 4 + sl] = (unsigned int)f2bfbits(ewd * gv)
                                 | ((unsigned int)f2bfbits(nsd * gv) << 16);
            }
        }
    }
    uint4* dst = (uint4*)(Op + (size_t)v * 96);
#pragma unroll
    for (int q = 0; q < 24; ++q) dst[q] = ((const uint4*)r)[q];
}

// ---------------------------------------------------------------------------
// K1: per-b transpose + pad: x[c][v] fp32 -> xin[v][c] bf16 + xin8[v][c] fp8.
// ---------------------------------------------------------------------------
__global__ void k_transpose(const float* __restrict__ x,
                            unsigned short* __restrict__ xin,
                            unsigned char* __restrict__ xin8) {
    x    += (size_t)blockIdx.y * 64 * NVP;
    xin  += (size_t)blockIdx.y * 64 * NV;
    xin8 += (size_t)blockIdx.y * 64 * NV;
    __shared__ float tile[64][65];
    int v0 = blockIdx.x * 64;
    int tx = threadIdx.x & 63;
    int ty = threadIdx.x >> 6;
    int v  = v0 + tx;
#pragma unroll
    for (int r = 0; r < 16; ++r) {
        int c = ty + r * 4;
        tile[tx][c] = (v < NVP) ? x[c * NVP + v] : 1.0f;
    }
    __syncthreads();
#pragma unroll
    for (int r = 0; r < 16; ++r) {
        int vl = ty + r * 4;
        int vv = v0 + vl;
        if (vv < NV) {
            float val = tile[vl][tx];
            xin [vv * 64 + tx] = f2bfbits(val);
            xin8[vv * 64 + tx] = one_fp8(val);
        }
    }
}

// ---------------------------------------------------------------------------
// K3: vertex kernel, now the ONLY heavy kernel. 512 thr, 32 v/block.
// 1-D grid, batch = bid & (nb-1): with nb=8 batch ≡ XCD (round-robin) so
// each XCD's xin8 (2.6 MB) is L2-resident; the 15.7 MB operator is
// L3-resident and shared by all XCDs.
// Phase 1 (lane=c): per vertex, 62 fp8 gathers driven by wide s_loads of
// the 384 B record. Phase 2: MFMA, unchanged. Epilogue: 128 B line stores.
// ---------------------------------------------------------------------------
__global__ void __launch_bounds__(512, 4) k_vertex(
    const unsigned short* __restrict__ xin,
    const unsigned char* __restrict__ xin8,
    const unsigned int* __restrict__ Op,
    const unsigned short* __restrict__ coeffsB,
    const float* __restrict__ bias,
    float* __restrict__ out,
    int nbm, int nbs) {
    int bid   = blockIdx.x;
    int batch = bid & nbm;
    int vb    = (bid >> nbs) * VPB;
    xin  += (size_t)batch * 64 * NV;
    xin8 += (size_t)batch * 64 * NV;
    out  += (size_t)batch * 64 * NV;

    __shared__ unsigned short feat[VPB * 264];   // 16896 B
    __shared__ float outs[VPB * 65];             // 8320 B
    int w    = __builtin_amdgcn_readfirstlane(threadIdx.x >> 6);  // 0..7
    int lane = threadIdx.x & 63;
    int c    = lane;

    // ---- phase 1: 8 waves x 4 vertices, composite-operator application ----
#pragma unroll
    for (int i = 0; i < 4; ++i) {
        int v   = vb + w * 4 + i;
        int vcs = __builtin_amdgcn_readfirstlane(v < NV ? v : NV - 1);
        const unsigned int* R = Op + (size_t)vcs * 96;   // uniform -> s_load

        float f0 = bfbits2f(xin[(size_t)vcs * 64 + c]);

        float lap = 0.f;
#pragma unroll
        for (int j = 0; j < 8; ++j) {
            int col = (R[j >> 1] >> ((j & 1) * 16)) & 0xffff;
            float lv = bfbits2f((unsigned short)(R[4 + (j >> 1)] >> ((j & 1) * 16)));
            lap += lv * fp8_lo((unsigned int)xin8[col * 64 + c]);
        }

        float ew = 0.f, ns = 0.f;
#pragma unroll
        for (int ch = 0; ch < 7; ++ch) {
            const unsigned int* C = R + 8 + ch * 12;
#pragma unroll
            for (int e = 0; e < 8; ++e) {
                int col = (C[e >> 1] >> ((e & 1) * 16)) & 0xffff;
                float xb = fp8_lo((unsigned int)xin8[col * 64 + c]);
                unsigned int vp = C[4 + e];
                ew += bfbits2f((unsigned short)vp) * xb;
                ns += bfbits2f((unsigned short)(vp >> 16)) * xb;
            }
        }

        int vloc = w * 4 + i;
        ushort4 p = make_ushort4(f2bfbits(f0), f2bfbits(lap),
                                 f2bfbits(ew), f2bfbits(ns));
        *(ushort4*)&feat[vloc * 264 + c * 4] = p;        // 8B, 2-way (free)
    }
    __syncthreads();

    // ---- phase 2: MFMA. wave w: o-tile = w&3, v-half = w>>2 ----
    int m = lane & 15, quad = lane >> 4;
    int ot = w & 3, vh = w >> 2;
    float bo = bias[ot * 16 + m];
    floatx4 acc = {bo, bo, bo, bo};
#pragma unroll
    for (int kk = 0; kk < 8; ++kk) {
        short8 a = *(const short8*)&feat[(vh * 16 + m) * 264 + kk * 32 + quad * 8];
        short8 bfr = *(const short8*)&coeffsB[((ot * 8 + kk) * 64 + lane) * 8];
        acc = __builtin_amdgcn_mfma_f32_16x16x32_bf16(a, bfr, acc, 0, 0, 0);
    }

    // ---- epilogue: C layout col=lane&15 (o), row=quad*4+reg (v) ----
#pragma unroll
    for (int r = 0; r < 4; ++r)
        outs[(vh * 16 + quad * 4 + r) * 65 + ot * 16 + m] = acc[r];
    __syncthreads();
    int vp = threadIdx.x & 31;          // 32 consecutive v -> 128 B lines
    int og = threadIdx.x >> 5;          // 0..15
    if (vb + vp < NV) {
#pragma unroll
        for (int r = 0; r < 4; ++r) {
            int o2 = og + r * 16;
            out[(size_t)o2 * NV + vb + vp] = outs[vp * 65 + o2];
        }
    }
}

// ---------------------------------------------------------------------------
extern "C" void kernel_launch(void* const* d_in, const int* in_sizes, int n_in,
                              void* d_out, int out_size, void* d_ws, size_t ws_size,
                              hipStream_t stream) {
    const float* x        = (const float*)d_in[0];
    const int*   G_cols   = (const int*)  d_in[2];
    const float* G_vals   = (const float*)d_in[3];
    const int*   L_cols   = (const int*)  d_in[5];
    const float* L_vals   = (const float*)d_in[6];
    const int*   F2V_cols = (const int*)  d_in[8];
    const float* F2V_vals = (const float*)d_in[9];
    const float* EW       = (const float*)d_in[10];
    const float* NS       = (const float*)d_in[11];
    const float* coeffs   = (const float*)d_in[12];
    const float* bias     = (const float*)d_in[13];
    float* out = (float*)d_out;

    char* ws = (char*)d_ws;
    const size_t xin_b = (size_t)NV * 64;        // elements per batch
    const size_t op_bytes = (size_t)NV * 384;    // 15.73 MB
    const size_t fixed = 65536 + op_bytes;
    // per-batch bytes: xin bf16 2*xin_b + xin8 1*xin_b
    size_t perb = 2 * xin_b + xin_b;
    int nb = (ws_size >= fixed + 8 * perb) ? 8
           : (ws_size >= fixed + 2 * perb) ? 2 : 1;
    int nbs = (nb == 8) ? 3 : (nb == 2) ? 1 : 0;

    unsigned short* coeffsB = (unsigned short*)ws;            // 32 KB
    unsigned int*   Opr  = (unsigned int*)(ws + 65536);       // 15.73 MB
    unsigned short* xin  = (unsigned short*)(ws + fixed);     // nb*5.25 MB
    unsigned char*  xin8 = (unsigned char*)(xin + (size_t)nb * xin_b); // nb*2.6MB

    k_coeffsB<<<64, 256, 0, stream>>>(coeffs, coeffsB);
    k_packOp<<<(NV + 255) / 256, 256, 0, stream>>>(L_cols, L_vals,
                                                   F2V_cols, F2V_vals,
                                                   G_cols, G_vals, EW, NS, Opr);
    const int nvb = (NV + VPB - 1) / VPB;        // 1281
    for (int b0 = 0; b0 < 8; b0 += nb) {
        dim3 gt(641, nb);
        k_transpose<<<gt, 256, 0, stream>>>(x + (size_t)b0 * 64 * NVP, xin, xin8);
        k_vertex<<<nvb * nb, 512, 0, stream>>>(xin, xin8, Opr, coeffsB, bias,
                                               out + (size_t)b0 * 64 * NV,
                                               nb - 1, nbs);
    }
}

// Round 4
// 308.385 us; speedup vs baseline: 1.2949x; 1.2949x over previous
//
#include <hip/hip_runtime.h>
#include <hip/hip_bf16.h>

typedef __hip_bfloat16 bf16;
typedef __attribute__((ext_vector_type(8))) short short8;
typedef __attribute__((ext_vector_type(4))) float floatx4;

#define NVP 10242
#define NV  40962
#define NF  81920
#define VPB 32
#define FPW 4   // faces per wave in k_facegrad

__device__ __forceinline__ float bfbits2f(unsigned short u) {
    union { unsigned int i; float f; } cv; cv.i = ((unsigned int)u) << 16;
    return cv.f;
}
__device__ __forceinline__ unsigned short f2bfbits(float f) {
    bf16 h = __float2bfloat16(f);
    return __builtin_bit_cast(unsigned short, h);
}
// fp8 e4m3 (OCP on gfx950)
__device__ __forceinline__ unsigned short pk_fp8(float a, float b) {
    int p = __builtin_amdgcn_cvt_pk_fp8_f32(a, b, 0, false);
    return (unsigned short)(p & 0xffff);
}
__device__ __forceinline__ unsigned char one_fp8(float a) {
    int p = __builtin_amdgcn_cvt_pk_fp8_f32(a, 0.f, 0, false);
    return (unsigned char)(p & 0xff);
}
__device__ __forceinline__ float fp8_lo(unsigned int u) {
    return __builtin_amdgcn_cvt_f32_fp8(u, 0);
}
__device__ __forceinline__ float fp8_hi(unsigned int u) {
    return __builtin_amdgcn_cvt_f32_fp8(u, 1);
}

// ---------------------------------------------------------------------------
// K0 (merged prep): blocks [0,64): coeffsB; [64,384): packG; [384,545): packV.
//
// coeffsB: [o][c][k] -> bf16 MFMA 16x16x32 B-fragment layout.
// Gpk per-face 128 B record: dw[0..8] 9 cols | dw[16..24] 9 vals
//                            dw[25..27] EW | dw[28..30] NS  (cols-first).
// Vpk per-vertex 128 B record: dw[0..6] 7 Lcols | dw[8..13] 6 F2Vcols
//                              dw[16..22] 7 Lvals | dw[24..29] 6 F2Vvals.
// ---------------------------------------------------------------------------
__global__ void k_prep(const float* __restrict__ coeffs,
                       unsigned short* __restrict__ coeffsB,
                       const int* __restrict__ G_cols,
                       const float* __restrict__ G_vals,
                       const float* __restrict__ EW,
                       const float* __restrict__ NS,
                       float* __restrict__ Gpk,
                       const int* __restrict__ L_cols,
                       const float* __restrict__ L_vals,
                       const int* __restrict__ F2V_cols,
                       const float* __restrict__ F2V_vals,
                       float* __restrict__ Vpk) {
    int b = blockIdx.x;
    if (b < 64) {
        int t = b * 256 + threadIdx.x;                 // 0..16383
        int j = t & 7, lane = (t >> 3) & 63, s = t >> 9;
        int ot = s >> 3, kk = s & 7;
        int o  = ot * 16 + (lane & 15);
        int kg = kk * 32 + (lane >> 4) * 8 + j;
        coeffsB[t] = f2bfbits(coeffs[o * 256 + kg]);
    } else if (b < 384) {
        int f = (b - 64) * 256 + threadIdx.x;          // NF/256 = 320 exact
        float r[32];
#pragma unroll
        for (int q = 0; q < 32; ++q) r[q] = 0.f;
#pragma unroll
        for (int d = 0; d < 3; ++d)
#pragma unroll
            for (int j = 0; j < 3; ++j) {
                int idx = (d * NF + f) * 3 + j;
                r[d * 3 + j]      = __int_as_float(G_cols[idx]);
                r[16 + d * 3 + j] = G_vals[idx];
            }
#pragma unroll
        for (int d = 0; d < 3; ++d) {
            r[25 + d] = EW[f * 3 + d];
            r[28 + d] = NS[f * 3 + d];
        }
        float4* dst = (float4*)(Gpk + (size_t)f * 32);
#pragma unroll
        for (int q = 0; q < 8; ++q) dst[q] = ((const float4*)r)[q];
    } else {
        int v = (b - 384) * 256 + threadIdx.x;
        if (v >= NV) return;
        float r[32];
#pragma unroll
        for (int q = 0; q < 32; ++q) r[q] = 0.f;
#pragma unroll
        for (int j = 0; j < 7; ++j) {
            r[j]      = __int_as_float(L_cols[v * 7 + j]);
            r[16 + j] = L_vals[v * 7 + j];
        }
#pragma unroll
        for (int j = 0; j < 6; ++j) {
            r[8 + j]  = __int_as_float(F2V_cols[v * 6 + j]);
            r[24 + j] = F2V_vals[v * 6 + j];
        }
        float4* dst = (float4*)(Vpk + (size_t)v * 32);
#pragma unroll
        for (int q = 0; q < 8; ++q) dst[q] = ((const float4*)r)[q];
    }
}

// ---------------------------------------------------------------------------
// K1: per-b transpose + pad: x[c][v] fp32 -> xin[v][c] bf16 + xin8[v][c] fp8.
// ---------------------------------------------------------------------------
__global__ void k_transpose(const float* __restrict__ x,
                            unsigned short* __restrict__ xin,
                            unsigned char* __restrict__ xin8) {
    x    += (size_t)blockIdx.y * 64 * NVP;
    xin  += (size_t)blockIdx.y * 64 * NV;
    xin8 += (size_t)blockIdx.y * 64 * NV;
    __shared__ float tile[64][65];
    int v0 = blockIdx.x * 64;
    int tx = threadIdx.x & 63;
    int ty = threadIdx.x >> 6;
    int v  = v0 + tx;
#pragma unroll
    for (int r = 0; r < 16; ++r) {
        int c = ty + r * 4;
        tile[tx][c] = (v < NVP) ? x[c * NVP + v] : 1.0f;
    }
    __syncthreads();
#pragma unroll
    for (int r = 0; r < 16; ++r) {
        int vl = ty + r * 4;
        int vv = v0 + vl;
        if (vv < NV) {
            float val = tile[vl][tx];
            xin [vv * 64 + tx] = f2bfbits(val);
            xin8[vv * 64 + tx] = one_fp8(val);
        }
    }
}

// ---------------------------------------------------------------------------
// K2: face gradients. 1-D grid, batch = bid&nbm -> batch ≡ XCD (round-robin)
// so xin8 (2.6 MB) is L2-resident and gfi is produced on its consumer XCD.
// Explicit 3-stage SoA: scalar cols -> 36 gathers in flight -> vals + math.
// ---------------------------------------------------------------------------
__global__ void __launch_bounds__(256, 4) k_facegrad(
    const unsigned char* __restrict__ xin8,
    const float* __restrict__ Gpk,
    unsigned short* __restrict__ gfi, int nbm, int nbs) {
    int batch = blockIdx.x & nbm;
    int fblk  = blockIdx.x >> nbs;
    xin8 += (size_t)batch * 64 * NV;
    gfi  += (size_t)batch * 64 * NF;
    int w  = __builtin_amdgcn_readfirstlane(threadIdx.x >> 6);
    int c  = threadIdx.x & 63;
    int f0 = (fblk * 4 + w) * FPW;

    // stage A: scalar col loads
    int gc[FPW][9];
#pragma unroll
    for (int i = 0; i < FPW; ++i) {
        const int* ri = (const int*)(Gpk + (size_t)(f0 + i) * 32);
#pragma unroll
        for (int j = 0; j < 9; ++j) gc[i][j] = ri[j];
    }
    // stage B: all 36 gathers in flight
    unsigned int xv[FPW][9];
#pragma unroll
    for (int i = 0; i < FPW; ++i)
#pragma unroll
        for (int j = 0; j < 9; ++j)
            xv[i][j] = xin8[(size_t)gc[i][j] * 64 + c];
    // stage C: vals + math + store
#pragma unroll
    for (int i = 0; i < FPW; ++i) {
        const float* rf = Gpk + (size_t)(f0 + i) * 32;
        float g0 = rf[16] * fp8_lo(xv[i][0]) + rf[17] * fp8_lo(xv[i][1])
                 + rf[18] * fp8_lo(xv[i][2]);
        float g1 = rf[19] * fp8_lo(xv[i][3]) + rf[20] * fp8_lo(xv[i][4])
                 + rf[21] * fp8_lo(xv[i][5]);
        float g2 = rf[22] * fp8_lo(xv[i][6]) + rf[23] * fp8_lo(xv[i][7])
                 + rf[24] * fp8_lo(xv[i][8]);
        float ew = g0 * rf[25] + g1 * rf[26] + g2 * rf[27];
        float ns = g0 * rf[28] + g1 * rf[29] + g2 * rf[30];
        gfi[(f0 + i) * 64 + c] = pk_fp8(ew, ns);         // 128 B/wave store
    }
}

// ---------------------------------------------------------------------------
// K3: vertex kernel. 512 thr, 32 v/block, 1-D grid (batch = bid&nbm ≡ XCD).
// Phase 1 explicit 3-stage SoA: scalar cols for 4 vertices -> ALL 56 vector
// gathers in flight -> vals + math. (Round-2's loop kept chains sequential:
// VGPR=36 proved only ~14 loads in flight.) launch_bounds(512,2): let VGPR
// grow to ~128 so the gather results fit in registers.
// Phase 2: wave (ot,vh) -> o-tile x v-half via 8x mfma 16x16x32 bf16.
// ---------------------------------------------------------------------------
__global__ void __launch_bounds__(512, 2) k_vertex(
    const unsigned short* __restrict__ xin,
    const unsigned char* __restrict__ xin8,
    const float* __restrict__ Vpk,
    const unsigned short* __restrict__ gfi,
    const unsigned short* __restrict__ coeffsB,
    const float* __restrict__ bias,
    float* __restrict__ out,
    int nbm, int nbs) {
    int batch = blockIdx.x & nbm;
    int vb    = (blockIdx.x >> nbs) * VPB;
    xin  += (size_t)batch * 64 * NV;
    xin8 += (size_t)batch * 64 * NV;
    gfi  += (size_t)batch * 64 * NF;
    out  += (size_t)batch * 64 * NV;

    __shared__ unsigned short feat[VPB * 264];   // 16896 B
    __shared__ float outs[VPB * 65];             // 8320 B
    int w    = __builtin_amdgcn_readfirstlane(threadIdx.x >> 6);  // 0..7
    int lane = threadIdx.x & 63;
    int c    = lane;

    int vcs[4];
#pragma unroll
    for (int i = 0; i < 4; ++i) {
        int v = vb + w * 4 + i;
        vcs[i] = __builtin_amdgcn_readfirstlane(v < NV ? v : NV - 1);
    }
    // stage A: scalar col loads (first half of each record)
    int lc[4][7], fc[4][6];
#pragma unroll
    for (int i = 0; i < 4; ++i) {
        const int* ri = (const int*)(Vpk + (size_t)vcs[i] * 32);
#pragma unroll
        for (int j = 0; j < 7; ++j) lc[i][j] = ri[j];
#pragma unroll
        for (int j = 0; j < 6; ++j) fc[i][j] = ri[8 + j];
    }
    // stage B: issue ALL 56 vector gathers
    unsigned int f0u[4], xl[4][7], gg[4][6];
#pragma unroll
    for (int i = 0; i < 4; ++i) {
        f0u[i] = xin[(size_t)vcs[i] * 64 + c];
#pragma unroll
        for (int j = 0; j < 7; ++j)
            xl[i][j] = xin8[(size_t)lc[i][j] * 64 + c];
#pragma unroll
        for (int j = 0; j < 6; ++j)
            gg[i][j] = gfi[(size_t)fc[i][j] * 64 + c];
    }
    // stage C: val loads + math + feat store
#pragma unroll
    for (int i = 0; i < 4; ++i) {
        const float* rv = Vpk + (size_t)vcs[i] * 32;
        float lap = 0.f;
#pragma unroll
        for (int j = 0; j < 7; ++j)
            lap += rv[16 + j] * fp8_lo(xl[i][j]);
        float ew = 0.f, ns = 0.f;
#pragma unroll
        for (int j = 0; j < 6; ++j) {
            float val = rv[24 + j];
            ew += val * fp8_lo(gg[i][j]);
            ns += val * fp8_hi(gg[i][j]);
        }
        ushort4 p = make_ushort4((unsigned short)f0u[i], f2bfbits(lap),
                                 f2bfbits(ew), f2bfbits(ns));
        *(ushort4*)&feat[(w * 4 + i) * 264 + c * 4] = p;  // 8B, 2-way (free)
    }
    __syncthreads();

    // ---- phase 2: MFMA. wave w: o-tile = w&3, v-half = w>>2 ----
    int m = lane & 15, quad = lane >> 4;
    int ot = w & 3, vh = w >> 2;
    float bo = bias[ot * 16 + m];
    floatx4 acc = {bo, bo, bo, bo};
#pragma unroll
    for (int kk = 0; kk < 8; ++kk) {
        short8 a = *(const short8*)&feat[(vh * 16 + m) * 264 + kk * 32 + quad * 8];
        short8 bfr = *(const short8*)&coeffsB[((ot * 8 + kk) * 64 + lane) * 8];
        acc = __builtin_amdgcn_mfma_f32_16x16x32_bf16(a, bfr, acc, 0, 0, 0);
    }

    // ---- epilogue: C layout col=lane&15 (o), row=quad*4+reg (v) ----
#pragma unroll
    for (int r = 0; r < 4; ++r)
        outs[(vh * 16 + quad * 4 + r) * 65 + ot * 16 + m] = acc[r];
    __syncthreads();
    int vp = threadIdx.x & 31;          // 32 consecutive v -> 128 B lines
    int og = threadIdx.x >> 5;          // 0..15
    if (vb + vp < NV) {
#pragma unroll
        for (int r = 0; r < 4; ++r) {
            int o2 = og + r * 16;
            out[(size_t)o2 * NV + vb + vp] = outs[vp * 65 + o2];
        }
    }
}

// ---------------------------------------------------------------------------
extern "C" void kernel_launch(void* const* d_in, const int* in_sizes, int n_in,
                              void* d_out, int out_size, void* d_ws, size_t ws_size,
                              hipStream_t stream) {
    const float* x        = (const float*)d_in[0];
    const int*   G_cols   = (const int*)  d_in[2];
    const float* G_vals   = (const float*)d_in[3];
    const int*   L_cols   = (const int*)  d_in[5];
    const float* L_vals   = (const float*)d_in[6];
    const int*   F2V_cols = (const int*)  d_in[8];
    const float* F2V_vals = (const float*)d_in[9];
    const float* EW       = (const float*)d_in[10];
    const float* NS       = (const float*)d_in[11];
    const float* coeffs   = (const float*)d_in[12];
    const float* bias     = (const float*)d_in[13];
    float* out = (float*)d_out;

    char* ws = (char*)d_ws;
    const size_t xin_b = (size_t)NV * 64;        // elements per batch
    const size_t gf_b  = (size_t)NF * 64;
    const size_t gpk_bytes = (size_t)NF * 128;   // 10.49 MB
    const size_t vpk_bytes = (size_t)NV * 128;   // 5.24 MB
    const size_t fixed = 65536 + gpk_bytes + vpk_bytes;
    // per-batch bytes: xin bf16 2*xin_b + gfi 2*gf_b + xin8 1*xin_b
    size_t perb = 2 * xin_b + 2 * gf_b + xin_b;
    int nb = (ws_size >= fixed + 8 * perb) ? 8
           : (ws_size >= fixed + 2 * perb) ? 2 : 1;
    int nbs = (nb == 8) ? 3 : (nb == 2) ? 1 : 0;

    unsigned short* coeffsB = (unsigned short*)ws;            // 32 KB
    float* Gpk = (float*)(ws + 65536);
    float* Vpk = Gpk + (size_t)NF * 32;
    unsigned short* xin  = (unsigned short*)(ws + fixed);     // nb*5.25 MB
    unsigned short* gfi  = xin + (size_t)nb * xin_b;          // nb*10.5 MB
    unsigned char*  xin8 = (unsigned char*)(gfi + (size_t)nb * gf_b); // nb*2.6MB

    k_prep<<<545, 256, 0, stream>>>(coeffs, coeffsB, G_cols, G_vals, EW, NS,
                                    Gpk, L_cols, L_vals, F2V_cols, F2V_vals,
                                    Vpk);
    const int nvb = (NV + VPB - 1) / VPB;        // 1281
    const int nfb = NF / (4 * FPW);              // 5120
    for (int b0 = 0; b0 < 8; b0 += nb) {
        dim3 gt(641, nb);
        k_transpose<<<gt, 256, 0, stream>>>(x + (size_t)b0 * 64 * NVP, xin, xin8);
        k_facegrad<<<nfb * nb, 256, 0, stream>>>(xin8, Gpk, gfi, nb - 1, nbs);
        k_vertex<<<nvb * nb, 512, 0, stream>>>(xin, xin8, Vpk, gfi, coeffsB,
                                               bias, out + (size_t)b0 * 64 * NV,
                                               nb - 1, nbs);
    }
}